// Round 7
// baseline (642.446 us; speedup 1.0000x reference)
//
#include <hip/hip_runtime.h>
#include <hip/hip_bf16.h>
#include <math.h>
#include <stdint.h>

#define N_TOK 4096
#define C_DIM 1024
#define E_NUM 16
#define I_DIM 256

typedef unsigned short ushort_t;
typedef __attribute__((ext_vector_type(8))) short bf16x8;
typedef __attribute__((ext_vector_type(4))) float f32x4;

#define AS1 __attribute__((address_space(1)))
#define AS3 __attribute__((address_space(3)))

__device__ __forceinline__ void glds16(const void* g, void* l) {
    __builtin_amdgcn_global_load_lds((const AS1 uint32_t*)g, (AS3 uint32_t*)l, 16, 0, 0);
}

__device__ __forceinline__ ushort_t bf16_rne(float v) {
    uint32_t u = __float_as_uint(v);
    u = (u + 0x7FFFu + ((u >> 16) & 1u)) >> 16;
    return (ushort_t)u;
}
__device__ __forceinline__ float bf16_val(ushort_t h) {
    return __uint_as_float(((uint32_t)h) << 16);
}
__device__ __forceinline__ float gelu_exact(float v) {
    return 0.5f * v * (1.0f + erff(v * 0.70710678118654752f));
}

// ============================================================================
// zero the per-expert counters (ws is poisoned each call)
// ============================================================================
__global__ __launch_bounds__(64) void smk_zero16(int* cnt) {
    if (threadIdx.x < 16) cnt[threadIdx.x] = 0;
}

// ============================================================================
// smk_split: fp32 [R][K] -> hi+lo split-panel format.
// k-panel p = 32 k's; row = 128B = 8 units of 16B; content label
// L = unit_pos ^ (r&7): L 0..3 = hi k-group L, L 4..7 = lo k-group L-4.
// ============================================================================
__global__ __launch_bounds__(256) void smk_split(
    const float* __restrict__ src, char* __restrict__ dst, int R, int kush)
{
    const int u  = blockIdx.x * 256 + threadIdx.x;
    const int ku = 1 << kush;
    const int r  = u >> kush;
    const int k8 = u & (ku - 1);
    const int p  = k8 >> 2;
    const int uh = (k8 & 3) ^ (r & 7);

    const float* s = src + ((size_t)r << (kush + 3)) + k8 * 8;
    float4 a = *(const float4*)(s);
    float4 b = *(const float4*)(s + 4);
    float f[8] = {a.x, a.y, a.z, a.w, b.x, b.y, b.z, b.w};

    uint4 hi4, lo4;
    ushort_t* hp = (ushort_t*)&hi4;
    ushort_t* lp = (ushort_t*)&lo4;
    #pragma unroll
    for (int j = 0; j < 8; ++j) {
        ushort_t h = bf16_rne(f[j]);
        hp[j] = h;
        lp[j] = bf16_rne(f[j] - bf16_val(h));
    }
    size_t ob = (((size_t)p * R + r) * 8 + uh) * 16;
    *(uint4*)(dst + ob)        = hi4;
    *(uint4*)(dst + (ob ^ 64)) = lo4;
}

// ============================================================================
// smk_splitBH: fp32 [R][K] -> hi-only DUAL-PANEL format (W1 B-side).
// ============================================================================
__global__ __launch_bounds__(256) void smk_splitBH(
    const float* __restrict__ src, char* __restrict__ dst, int R, int kush)
{
    const int u  = blockIdx.x * 256 + threadIdx.x;
    const int ku = 1 << kush;
    const int r  = u >> kush;
    const int k8 = u & (ku - 1);
    const int p  = k8 >> 2;
    const int q  = p >> 1;
    const int uh = ((k8 & 3) | ((p & 1) << 2)) ^ (r & 7);

    const float* s = src + ((size_t)r << (kush + 3)) + k8 * 8;
    float4 a = *(const float4*)(s);
    float4 b = *(const float4*)(s + 4);
    float f[8] = {a.x, a.y, a.z, a.w, b.x, b.y, b.z, b.w};

    uint4 hi4;
    ushort_t* hp = (ushort_t*)&hi4;
    #pragma unroll
    for (int j = 0; j < 8; ++j) hp[j] = bf16_rne(f[j]);

    *(uint4*)(dst + (((size_t)q * R + r) * 8 + uh) * 16) = hi4;
}

// ============================================================================
// gate: 16 tokens per block, sim staged in LDS; builds per-expert token lists.
// ============================================================================
__global__ __launch_bounds__(256) void smk_gate2(
    const float* __restrict__ x, const float* __restrict__ sim,
    const float* __restrict__ thr,
    float* __restrict__ scores, float* __restrict__ kpt,
    int* __restrict__ lists, int* __restrict__ cnt)
{
    __shared__ __align__(16) float ss[C_DIM * E_NUM];
    __shared__ float pm[16][17];
    __shared__ float inv_ns[E_NUM];
    __shared__ float mrow[16][17];

    const int tid = threadIdx.x;
    #pragma unroll
    for (int q = 0; q < 16; ++q)
        *(float4*)&ss[q * 1024 + tid * 4] = *(const float4*)&sim[q * 1024 + tid * 4];
    __syncthreads();

    const int e = tid & 15;
    const int g = tid >> 4;
    float ps = 0.f;
    for (int c = g; c < C_DIM; c += 16) {
        float v = ss[c * 16 + e];
        ps = fmaf(v, v, ps);
    }
    pm[g][e] = ps;
    __syncthreads();
    if (tid < 16) {
        float s = 0.f;
        #pragma unroll
        for (int gg = 0; gg < 16; ++gg) s += pm[gg][tid];
        inv_ns[tid] = 1.f / fmaxf(sqrtf(s), 1e-12f);
    }
    __syncthreads();

    const int t = blockIdx.x * 16 + g;
    const float* xr = x + (size_t)t * C_DIM;
    float dot = 0.f, sq = 0.f;
    for (int c = 0; c < C_DIM; c += 4) {
        float4 xv = *(const float4*)&xr[c];
        dot = fmaf(xv.x, ss[(c + 0) * 16 + e], dot);
        dot = fmaf(xv.y, ss[(c + 1) * 16 + e], dot);
        dot = fmaf(xv.z, ss[(c + 2) * 16 + e], dot);
        dot = fmaf(xv.w, ss[(c + 3) * 16 + e], dot);
        sq  = fmaf(xv.x, xv.x, sq); sq = fmaf(xv.y, xv.y, sq);
        sq  = fmaf(xv.z, xv.z, sq); sq = fmaf(xv.w, xv.w, sq);
    }
    float sc = dot * inv_ns[e] * (1.f / fmaxf(sqrtf(sq), 1e-12f));
    scores[(size_t)t * E_NUM + e] = sc;
    const bool act = sc > thr[0];
    if (act && lists != nullptr) {
        int pos = atomicAdd(&cnt[e], 1);
        lists[e * N_TOK + pos] = t;
    }
    mrow[g][e] = act ? 1.f : 0.f;
    __syncthreads();
    if (e == 0) {
        float k = 0.f;
        #pragma unroll
        for (int ee = 0; ee < 16; ++ee) k += mrow[g][ee];
        kpt[t] = k;
    }
}

// ============================================================================
// COMPACTED FFN1: H[slot] = gelu(X[list[slot]] @ W1[e]^T).
// A gathered from split-X via per-lane global src with swizzle correction
// v ^ ((s ^ tr)&7); LDS dest stays linear (wave-uniform + lane*16).
// ============================================================================
__global__ __launch_bounds__(256) void smk_ffn1_mfma_c(
    const char* __restrict__ Xs, const char* __restrict__ W1h,
    char* __restrict__ Hsh, const int* __restrict__ lists,
    const int* __restrict__ cnt)
{
    __shared__ char As[16384];
    __shared__ char Bs[16384];

    const int e  = blockIdx.z;
    const int nt = cnt[e];
    const int t0 = blockIdx.x * 128;
    if (t0 >= nt) return;
    const int i0 = blockIdx.y * 128;
    const int tid  = threadIdx.x;
    const int lane = tid & 63;
    const int w    = tid >> 6;
    const int wr   = w >> 1, wc = w & 1;

    const int srow = tid >> 3;    // LDS row within quarter (0..31)
    const int v    = tid & 7;     // unit within row
    const int* le  = lists + e * N_TOK;
    uint32_t abase[4];
    #pragma unroll
    for (int q = 0; q < 4; ++q) {
        int s    = q * 32 + srow;                 // LDS-local row 0..127
        int slot = t0 + s;
        int tr   = le[(slot < nt) ? slot : (nt - 1)];
        abase[q] = (uint32_t)(tr * 128 + (v ^ ((s ^ tr) & 7)) * 16);
    }

    f32x4 acc[4][4];
    #pragma unroll
    for (int mi = 0; mi < 4; ++mi)
        #pragma unroll
        for (int ni = 0; ni < 4; ++ni)
            acc[mi][ni] = (f32x4){0.f, 0.f, 0.f, 0.f};

    const char* Bg = W1h + ((size_t)(e * 256) + i0) * 128 + tid * 16;

    for (int p = 0; p < 32; ++p) {
        __syncthreads();
        const char* gp = Xs + (size_t)p * (4096 * 128);
        #pragma unroll
        for (int q = 0; q < 4; ++q)
            glds16(gp + abase[q], As + q * 4096 + tid * 16);
        if ((p & 1) == 0) {
            const char* gb = Bg + (size_t)(p >> 1) * (4096 * 128);
            #pragma unroll
            for (int q = 0; q < 4; ++q)
                glds16(gb + q * 4096, Bs + q * 4096 + tid * 16);
        }
        __syncthreads();

        bf16x8 ah[4], al[4], bh[4];
        #pragma unroll
        for (int mi = 0; mi < 4; ++mi) {
            int r   = wr * 64 + mi * 16 + (lane & 15);
            int ubh = (((lane >> 4)    ) ^ (r & 7)) * 16;
            int ubl = (((lane >> 4) | 4) ^ (r & 7)) * 16;
            ah[mi] = *(const bf16x8*)(As + r * 128 + ubh);
            al[mi] = *(const bf16x8*)(As + r * 128 + ubl);
        }
        const int ubsel = (lane >> 4) | ((p & 1) << 2);
        #pragma unroll
        for (int ni = 0; ni < 4; ++ni) {
            int r  = wc * 64 + ni * 16 + (lane & 15);
            int ub = (ubsel ^ (r & 7)) * 16;
            bh[ni] = *(const bf16x8*)(Bs + r * 128 + ub);
        }
        #pragma unroll
        for (int mi = 0; mi < 4; ++mi)
            #pragma unroll
            for (int ni = 0; ni < 4; ++ni) {
                acc[mi][ni] = __builtin_amdgcn_mfma_f32_16x16x32_bf16(ah[mi], bh[ni], acc[mi][ni], 0, 0, 0);
                acc[mi][ni] = __builtin_amdgcn_mfma_f32_16x16x32_bf16(al[mi], bh[ni], acc[mi][ni], 0, 0, 0);
            }
    }

    // epilogue: gelu, bf16 hi, dual-panel Hsh indexed by SLOT (padded slots
    // write garbage that is never consumed for output)
    const int rb = (lane >> 4) * 4;
    #pragma unroll
    for (int mi = 0; mi < 4; ++mi)
        #pragma unroll
        for (int ni = 0; ni < 4; ++ni) {
            int ig = i0 + wc * 64 + ni * 16 + (lane & 15);
            int pp = ig >> 5, qq = pp >> 1;
            int uu = ((ig >> 3) & 3) | ((pp & 1) << 2);
            #pragma unroll
            for (int j = 0; j < 4; ++j) {
                int slot = t0 + wr * 64 + mi * 16 + rb + j;
                float vv = gelu_exact(acc[mi][ni][j]);
                size_t ob = (((size_t)((e * 4 + qq) * 4096 + slot)) * 8 + (uu ^ (slot & 7))) * 16
                          + (ig & 7) * 2;
                *(ushort_t*)(Hsh + ob) = bf16_rne(vv);
            }
        }
}

// ============================================================================
// COMPACTED FFN2: eo[list[slot], e, :] = H[slot] @ W2[e]^T (mask implicit).
// ============================================================================
__global__ __launch_bounds__(256) void smk_ffn2_mfma_c(
    const char* __restrict__ Hsh, const char* __restrict__ W2s,
    const int* __restrict__ lists, const int* __restrict__ cnt,
    float* __restrict__ eo)
{
    __shared__ char As[16384];
    __shared__ char Bs[16384];

    const int e  = blockIdx.z;
    const int nt = cnt[e];
    const int t0 = blockIdx.x * 128;
    if (t0 >= nt) return;
    const int c0 = blockIdx.y * 128;
    const int tid  = threadIdx.x;
    const int lane = tid & 63;
    const int w    = tid >> 6;
    const int wr   = w >> 1, wc = w & 1;

    f32x4 acc[4][4];
    #pragma unroll
    for (int mi = 0; mi < 4; ++mi)
        #pragma unroll
        for (int ni = 0; ni < 4; ++ni)
            acc[mi][ni] = (f32x4){0.f, 0.f, 0.f, 0.f};

    const char* Ag = Hsh + ((size_t)(e * 4) * 4096 + t0) * 128 + tid * 16;
    const char* Bg = W2s + ((size_t)(e * 1024) + c0) * 128 + tid * 16;

    for (int p = 0; p < 8; ++p) {
        __syncthreads();
        if ((p & 1) == 0) {
            const char* ga = Ag + (size_t)(p >> 1) * (4096 * 128);
            #pragma unroll
            for (int q = 0; q < 4; ++q)
                glds16(ga + q * 4096, As + q * 4096 + tid * 16);
        }
        const char* gb = Bg + (size_t)p * (16384 * 128);
        #pragma unroll
        for (int q = 0; q < 4; ++q)
            glds16(gb + q * 4096, Bs + q * 4096 + tid * 16);
        __syncthreads();

        bf16x8 ah[4], bh[4], bl[4];
        const int uasel = (lane >> 4) | ((p & 1) << 2);
        #pragma unroll
        for (int mi = 0; mi < 4; ++mi) {
            int r  = wr * 64 + mi * 16 + (lane & 15);
            int ua = (uasel ^ (r & 7)) * 16;
            ah[mi] = *(const bf16x8*)(As + r * 128 + ua);
        }
        #pragma unroll
        for (int ni = 0; ni < 4; ++ni) {
            int r   = wc * 64 + ni * 16 + (lane & 15);
            int ubh = (((lane >> 4)    ) ^ (r & 7)) * 16;
            int ubl = (((lane >> 4) | 4) ^ (r & 7)) * 16;
            bh[ni] = *(const bf16x8*)(Bs + r * 128 + ubh);
            bl[ni] = *(const bf16x8*)(Bs + r * 128 + ubl);
        }
        #pragma unroll
        for (int mi = 0; mi < 4; ++mi)
            #pragma unroll
            for (int ni = 0; ni < 4; ++ni) {
                acc[mi][ni] = __builtin_amdgcn_mfma_f32_16x16x32_bf16(ah[mi], bh[ni], acc[mi][ni], 0, 0, 0);
                acc[mi][ni] = __builtin_amdgcn_mfma_f32_16x16x32_bf16(ah[mi], bl[ni], acc[mi][ni], 0, 0, 0);
            }
    }

    const int* le = lists + e * N_TOK;
    const int rb = (lane >> 4) * 4;
    #pragma unroll
    for (int mi = 0; mi < 4; ++mi)
        #pragma unroll
        for (int j = 0; j < 4; ++j) {
            int slot = t0 + wr * 64 + mi * 16 + rb + j;
            if (slot < nt) {
                int tr = le[slot];
                float* dst = eo + ((size_t)tr * E_NUM + e) * C_DIM + c0 + wc * 64 + (lane & 15);
                #pragma unroll
                for (int ni = 0; ni < 4; ++ni)
                    dst[ni * 16] = acc[mi][ni][j];
            }
        }
}

// ============================================================================
// zero-fill: write zeros to INACTIVE eo rows only (active rows come from ffn2)
// ============================================================================
__global__ __launch_bounds__(256) void smk_zerofill(
    const float* __restrict__ scores, const float* __restrict__ thr,
    float* __restrict__ eo)
{
    const int row = blockIdx.x;                 // row = t*16 + e
    if (scores[row] > thr[0]) return;
    float4 z = {0.f, 0.f, 0.f, 0.f};
    *(float4*)&eo[(size_t)row * C_DIM + threadIdx.x * 4] = z;
}

// ============================================================================
// combine: final[t] = sum over ACTIVE e of eo[t,e,:]  (inactive rows are zero)
// ============================================================================
__global__ __launch_bounds__(256) void smk_combine2(
    const float* __restrict__ eo, const float* __restrict__ scores,
    const float* __restrict__ thr, float* __restrict__ fin)
{
    const int t = blockIdx.x;
    __shared__ unsigned am;
    if (threadIdx.x == 0) {
        unsigned m = 0;
        float th = thr[0];
        #pragma unroll
        for (int e = 0; e < E_NUM; ++e)
            if (scores[t * E_NUM + e] > th) m |= (1u << e);
        am = m;
    }
    __syncthreads();
    const unsigned m = am;
    const float* p = eo + (size_t)t * E_NUM * C_DIM + threadIdx.x * 4;
    float4 s = {0.f, 0.f, 0.f, 0.f};
    #pragma unroll
    for (int e = 0; e < E_NUM; ++e) {
        if (m & (1u << e)) {
            float4 v = *(const float4*)&p[(size_t)e * C_DIM];
            s.x += v.x; s.y += v.y; s.z += v.z; s.w += v.w;
        }
    }
    *(float4*)&fin[(size_t)t * C_DIM + threadIdx.x * 4] = s;
}

// ============================================================================
// DENSE MFMA path (round-6, proven) — fallback if ws lacks list space
// ============================================================================
__global__ __launch_bounds__(256) void smk_ffn1_mfma(
    const char* __restrict__ Xs, const char* __restrict__ W1h,
    char* __restrict__ Hsh)
{
    __shared__ char As[16384];
    __shared__ char Bs[16384];

    const int e  = blockIdx.z;
    const int t0 = blockIdx.x * 128;
    const int i0 = blockIdx.y * 128;
    const int tid  = threadIdx.x;
    const int lane = tid & 63;
    const int w    = tid >> 6;
    const int wr   = w >> 1, wc = w & 1;

    f32x4 acc[4][4];
    #pragma unroll
    for (int mi = 0; mi < 4; ++mi)
        #pragma unroll
        for (int ni = 0; ni < 4; ++ni)
            acc[mi][ni] = (f32x4){0.f, 0.f, 0.f, 0.f};

    const char* Ag = Xs  + (size_t)t0 * 128 + tid * 16;
    const char* Bg = W1h + ((size_t)(e * 256) + i0) * 128 + tid * 16;

    for (int p = 0; p < 32; ++p) {
        __syncthreads();
        const char* ga = Ag + (size_t)p * (4096 * 128);
        #pragma unroll
        for (int q = 0; q < 4; ++q)
            glds16(ga + q * 4096, As + q * 4096 + tid * 16);
        if ((p & 1) == 0) {
            const char* gb = Bg + (size_t)(p >> 1) * (4096 * 128);
            #pragma unroll
            for (int q = 0; q < 4; ++q)
                glds16(gb + q * 4096, Bs + q * 4096 + tid * 16);
        }
        __syncthreads();

        bf16x8 ah[4], al[4], bh[4];
        #pragma unroll
        for (int mi = 0; mi < 4; ++mi) {
            int r   = wr * 64 + mi * 16 + (lane & 15);
            int ubh = (((lane >> 4)    ) ^ (r & 7)) * 16;
            int ubl = (((lane >> 4) | 4) ^ (r & 7)) * 16;
            ah[mi] = *(const bf16x8*)(As + r * 128 + ubh);
            al[mi] = *(const bf16x8*)(As + r * 128 + ubl);
        }
        const int ubsel = (lane >> 4) | ((p & 1) << 2);
        #pragma unroll
        for (int ni = 0; ni < 4; ++ni) {
            int r  = wc * 64 + ni * 16 + (lane & 15);
            int ub = (ubsel ^ (r & 7)) * 16;
            bh[ni] = *(const bf16x8*)(Bs + r * 128 + ub);
        }
        #pragma unroll
        for (int mi = 0; mi < 4; ++mi)
            #pragma unroll
            for (int ni = 0; ni < 4; ++ni) {
                acc[mi][ni] = __builtin_amdgcn_mfma_f32_16x16x32_bf16(ah[mi], bh[ni], acc[mi][ni], 0, 0, 0);
                acc[mi][ni] = __builtin_amdgcn_mfma_f32_16x16x32_bf16(al[mi], bh[ni], acc[mi][ni], 0, 0, 0);
            }
    }

    const int rb = (lane >> 4) * 4;
    #pragma unroll
    for (int mi = 0; mi < 4; ++mi)
        #pragma unroll
        for (int ni = 0; ni < 4; ++ni) {
            int ig = i0 + wc * 64 + ni * 16 + (lane & 15);
            int pp = ig >> 5, qq = pp >> 1;
            int uu = ((ig >> 3) & 3) | ((pp & 1) << 2);
            #pragma unroll
            for (int j = 0; j < 4; ++j) {
                int t = t0 + wr * 64 + mi * 16 + rb + j;
                float vv = gelu_exact(acc[mi][ni][j]);
                size_t ob = (((size_t)((e * 4 + qq) * 4096 + t)) * 8 + (uu ^ (t & 7))) * 16
                          + (ig & 7) * 2;
                *(ushort_t*)(Hsh + ob) = bf16_rne(vv);
            }
        }
}

__global__ __launch_bounds__(256) void smk_ffn2_mfma(
    const char* __restrict__ Hsh, const char* __restrict__ W2s,
    const float* __restrict__ scores, const float* __restrict__ thr,
    float* __restrict__ eo)
{
    __shared__ char As[16384];
    __shared__ char Bs[16384];

    const int e  = blockIdx.z;
    const int t0 = blockIdx.x * 128;
    const int c0 = blockIdx.y * 128;
    const int tid  = threadIdx.x;
    const int lane = tid & 63;
    const int w    = tid >> 6;
    const int wr   = w >> 1, wc = w & 1;

    f32x4 acc[4][4];
    #pragma unroll
    for (int mi = 0; mi < 4; ++mi)
        #pragma unroll
        for (int ni = 0; ni < 4; ++ni)
            acc[mi][ni] = (f32x4){0.f, 0.f, 0.f, 0.f};

    const char* Ag = Hsh + ((size_t)(e * 4) * 4096 + t0) * 128 + tid * 16;
    const char* Bg = W2s + ((size_t)(e * 1024) + c0) * 128 + tid * 16;

    for (int p = 0; p < 8; ++p) {
        __syncthreads();
        if ((p & 1) == 0) {
            const char* ga = Ag + (size_t)(p >> 1) * (4096 * 128);
            #pragma unroll
            for (int q = 0; q < 4; ++q)
                glds16(ga + q * 4096, As + q * 4096 + tid * 16);
        }
        const char* gb = Bg + (size_t)p * (16384 * 128);
        #pragma unroll
        for (int q = 0; q < 4; ++q)
            glds16(gb + q * 4096, Bs + q * 4096 + tid * 16);
        __syncthreads();

        bf16x8 ah[4], bh[4], bl[4];
        const int uasel = (lane >> 4) | ((p & 1) << 2);
        #pragma unroll
        for (int mi = 0; mi < 4; ++mi) {
            int r  = wr * 64 + mi * 16 + (lane & 15);
            int ua = (uasel ^ (r & 7)) * 16;
            ah[mi] = *(const bf16x8*)(As + r * 128 + ua);
        }
        #pragma unroll
        for (int ni = 0; ni < 4; ++ni) {
            int r   = wc * 64 + ni * 16 + (lane & 15);
            int ubh = (((lane >> 4)    ) ^ (r & 7)) * 16;
            int ubl = (((lane >> 4) | 4) ^ (r & 7)) * 16;
            bh[ni] = *(const bf16x8*)(Bs + r * 128 + ubh);
            bl[ni] = *(const bf16x8*)(Bs + r * 128 + ubl);
        }
        #pragma unroll
        for (int mi = 0; mi < 4; ++mi)
            #pragma unroll
            for (int ni = 0; ni < 4; ++ni) {
                acc[mi][ni] = __builtin_amdgcn_mfma_f32_16x16x32_bf16(ah[mi], bh[ni], acc[mi][ni], 0, 0, 0);
                acc[mi][ni] = __builtin_amdgcn_mfma_f32_16x16x32_bf16(ah[mi], bl[ni], acc[mi][ni], 0, 0, 0);
            }
    }

    const float th = thr[0];
    const int rb = (lane >> 4) * 4;
    float msk[4][4];
    #pragma unroll
    for (int mi = 0; mi < 4; ++mi)
        #pragma unroll
        for (int j = 0; j < 4; ++j) {
            int t = t0 + wr * 64 + mi * 16 + rb + j;
            msk[mi][j] = (scores[(size_t)t * E_NUM + e] > th) ? 1.f : 0.f;
        }
    #pragma unroll
    for (int mi = 0; mi < 4; ++mi)
        #pragma unroll
        for (int ni = 0; ni < 4; ++ni) {
            int c = c0 + wc * 64 + ni * 16 + (lane & 15);
            #pragma unroll
            for (int j = 0; j < 4; ++j) {
                int t = t0 + wr * 64 + mi * 16 + rb + j;
                eo[((size_t)t * E_NUM + e) * C_DIM + c] = acc[mi][ni][j] * msk[mi][j];
            }
        }
}

// ============================================================================
// fp32 fallback path — used only if ws too small for any MFMA path
// ============================================================================
#define BM 64
#define BN 64
#define KC 16
#define LDP 68

__global__ __launch_bounds__(256) void smk_ffn1(
    const float* __restrict__ X, const float* __restrict__ W1,
    float* __restrict__ H, int eh, int ez0)
{
    const int e  = blockIdx.z + ez0;
    const int t0 = blockIdx.x * BM;
    const int i0 = blockIdx.y * BN;
    const float* Ap = X + (size_t)t0 * C_DIM;
    const float* Bp = W1 + ((size_t)e * I_DIM + i0) * C_DIM;
    __shared__ __align__(16) float As[KC][LDP];
    __shared__ __align__(16) float Bs[KC][LDP];
    const int tid = threadIdx.x;
    const int tx = tid & 15, ty = tid >> 4;
    const int lm = tid >> 2;
    const int lk = (tid & 3) * 4;
    float acc[4][4] = {};
    for (int k0 = 0; k0 < C_DIM; k0 += KC) {
        float4 av = *(const float4*)&Ap[(size_t)lm * C_DIM + k0 + lk];
        float4 bv = *(const float4*)&Bp[(size_t)lm * C_DIM + k0 + lk];
        __syncthreads();
        As[lk + 0][lm] = av.x; As[lk + 1][lm] = av.y;
        As[lk + 2][lm] = av.z; As[lk + 3][lm] = av.w;
        Bs[lk + 0][lm] = bv.x; Bs[lk + 1][lm] = bv.y;
        Bs[lk + 2][lm] = bv.z; Bs[lk + 3][lm] = bv.w;
        __syncthreads();
        #pragma unroll
        for (int k = 0; k < KC; ++k) {
            float4 a4 = *(const float4*)&As[k][ty * 4];
            float4 b4 = *(const float4*)&Bs[k][tx * 4];
            float a[4] = {a4.x, a4.y, a4.z, a4.w};
            float b[4] = {b4.x, b4.y, b4.z, b4.w};
            #pragma unroll
            for (int i = 0; i < 4; ++i)
                #pragma unroll
                for (int j = 0; j < 4; ++j)
                    acc[i][j] = fmaf(a[i], b[j], acc[i][j]);
        }
    }
    const size_t hrow = (size_t)eh * I_DIM;
    float* Hp = H + ((eh == E_NUM) ? (size_t)e * I_DIM : 0);
    #pragma unroll
    for (int i = 0; i < 4; ++i) {
        int t = t0 + ty * 4 + i;
        float4 o;
        o.x = gelu_exact(acc[i][0]); o.y = gelu_exact(acc[i][1]);
        o.z = gelu_exact(acc[i][2]); o.w = gelu_exact(acc[i][3]);
        *(float4*)&Hp[(size_t)t * hrow + i0 + tx * 4] = o;
    }
}

__global__ __launch_bounds__(256) void smk_ffn2(
    const float* __restrict__ Hst, const float* __restrict__ W2,
    const float* __restrict__ scores, const float* __restrict__ thr,
    float* __restrict__ eo, int eh, int ez0)
{
    const int e  = blockIdx.z + ez0;
    const int t0 = blockIdx.x * BM;
    const int c0 = blockIdx.y * BN;
    const size_t hrow = (size_t)eh * I_DIM;
    const float* Ap = Hst + ((eh == E_NUM) ? (size_t)e * I_DIM : 0) + (size_t)t0 * hrow;
    const float* Bp = W2 + ((size_t)e * C_DIM + c0) * I_DIM;
    __shared__ __align__(16) float As[KC][LDP];
    __shared__ __align__(16) float Bs[KC][LDP];
    const int tid = threadIdx.x;
    const int tx = tid & 15, ty = tid >> 4;
    const int lm = tid >> 2;
    const int lk = (tid & 3) * 4;
    float acc[4][4] = {};
    for (int k0 = 0; k0 < I_DIM; k0 += KC) {
        float4 av = *(const float4*)&Ap[(size_t)lm * hrow + k0 + lk];
        float4 bv = *(const float4*)&Bp[(size_t)lm * I_DIM + k0 + lk];
        __syncthreads();
        As[lk + 0][lm] = av.x; As[lk + 1][lm] = av.y;
        As[lk + 2][lm] = av.z; As[lk + 3][lm] = av.w;
        Bs[lk + 0][lm] = bv.x; Bs[lk + 1][lm] = bv.y;
        Bs[lk + 2][lm] = bv.z; Bs[lk + 3][lm] = bv.w;
        __syncthreads();
        #pragma unroll
        for (int k = 0; k < KC; ++k) {
            float4 a4 = *(const float4*)&As[k][ty * 4];
            float4 b4 = *(const float4*)&Bs[k][tx * 4];
            float a[4] = {a4.x, a4.y, a4.z, a4.w};
            float b[4] = {b4.x, b4.y, b4.z, b4.w};
            #pragma unroll
            for (int i = 0; i < 4; ++i)
                #pragma unroll
                for (int j = 0; j < 4; ++j)
                    acc[i][j] = fmaf(a[i], b[j], acc[i][j]);
        }
    }
    const float th = thr[0];
    #pragma unroll
    for (int i = 0; i < 4; ++i) {
        int t = t0 + ty * 4 + i;
        float m = (scores[(size_t)t * E_NUM + e] > th) ? 1.f : 0.f;
        float4 o;
        o.x = acc[i][0] * m; o.y = acc[i][1] * m;
        o.z = acc[i][2] * m; o.w = acc[i][3] * m;
        *(float4*)&eo[((size_t)t * E_NUM + e) * C_DIM + c0 + tx * 4] = o;
    }
}

// ============================================================================
extern "C" void kernel_launch(void* const* d_in, const int* in_sizes, int n_in,
                              void* d_out, int out_size, void* d_ws, size_t ws_size,
                              hipStream_t stream) {
    const float* x   = (const float*)d_in[0];
    const float* sim = (const float*)d_in[1];
    const float* thr = (const float*)d_in[2];
    const float* W1  = (const float*)d_in[3];
    const float* W2  = (const float*)d_in[4];

    float* out    = (float*)d_out;
    float* fin    = out;
    float* scores = out + (size_t)N_TOK * C_DIM;
    float* eo     = scores + (size_t)N_TOK * E_NUM;
    float* kpt    = eo + (size_t)N_TOK * E_NUM * C_DIM;

    const size_t SZ_XS  = 16777216;  // X hi+lo:  32p x 4096 x 128B
    const size_t SZ_W1H = 8388608;   // W1 hi:    16q x 4096 x 128B
    const size_t SZ_W2S = 16777216;  // W2 hi+lo:  8p x 16384 x 128B
    const size_t SZ_HSH = 33554432;  // H hi: 16e x 4q x 4096slots x 128B
    const size_t SZ_LST = (size_t)E_NUM * N_TOK * sizeof(int);  // 262144
    const size_t WS_MFMA = SZ_XS + SZ_W1H + SZ_W2S + SZ_HSH;    // 75,497,472
    const size_t WS_FULL = WS_MFMA + SZ_LST + 256;              // 75,759,872

    char* Xs  = (char*)d_ws;
    char* W1h = Xs + SZ_XS;
    char* W2s = W1h + SZ_W1H;
    char* Hsh = W2s + SZ_W2S;
    int*  lists = (int*)(Hsh + SZ_HSH);
    int*  cnt   = lists + E_NUM * N_TOK;

    if (ws_size >= WS_FULL) {
        // ---- compacted MFMA path ----
        smk_zero16<<<1, 64, 0, stream>>>(cnt);
        smk_gate2<<<N_TOK / 16, 256, 0, stream>>>(x, sim, thr, scores, kpt, lists, cnt);

        smk_split  <<<2048, 256, 0, stream>>>(x,  Xs,  4096,  7);
        smk_splitBH<<<2048, 256, 0, stream>>>(W1, W1h, 4096,  7);
        smk_split  <<<2048, 256, 0, stream>>>(W2, W2s, 16384, 5);

        dim3 g1(32, 2, 16);
        smk_ffn1_mfma_c<<<g1, 256, 0, stream>>>(Xs, W1h, Hsh, lists, cnt);
        dim3 g2(32, 8, 16);
        smk_ffn2_mfma_c<<<g2, 256, 0, stream>>>(Hsh, W2s, lists, cnt, eo);

        smk_zerofill<<<N_TOK * E_NUM, 256, 0, stream>>>(scores, thr, eo);
        smk_combine2<<<N_TOK, 256, 0, stream>>>(eo, scores, thr, fin);
    } else if (ws_size >= WS_MFMA) {
        // ---- dense MFMA path (round 6) ----
        smk_gate2<<<N_TOK / 16, 256, 0, stream>>>(x, sim, thr, scores, kpt, nullptr, nullptr);
        smk_split  <<<2048, 256, 0, stream>>>(x,  Xs,  4096,  7);
        smk_splitBH<<<2048, 256, 0, stream>>>(W1, W1h, 4096,  7);
        smk_split  <<<2048, 256, 0, stream>>>(W2, W2s, 16384, 5);
        dim3 g1(32, 2, 16);
        smk_ffn1_mfma<<<g1, 256, 0, stream>>>(Xs, W1h, Hsh);
        dim3 g2(32, 8, 16);
        smk_ffn2_mfma<<<g2, 256, 0, stream>>>(Hsh, W2s, scores, thr, eo);
        smk_combine2<<<N_TOK, 256, 0, stream>>>(eo, scores, thr, fin);
    } else {
        // ---- fp32 fallback ----
        smk_gate2<<<N_TOK / 16, 256, 0, stream>>>(x, sim, thr, scores, kpt, nullptr, nullptr);
        const size_t needH = (size_t)N_TOK * E_NUM * I_DIM * sizeof(float);
        if (ws_size >= needH) {
            float* H = (float*)d_ws;
            dim3 g1(N_TOK / BM, I_DIM / BN, E_NUM);
            smk_ffn1<<<g1, 256, 0, stream>>>(x, W1, H, E_NUM, 0);
            dim3 g2(N_TOK / BM, C_DIM / BN, E_NUM);
            smk_ffn2<<<g2, 256, 0, stream>>>(H, W2, scores, thr, eo, E_NUM, 0);
        } else {
            float* H = fin;
            for (int e = 0; e < E_NUM; ++e) {
                dim3 g1(N_TOK / BM, I_DIM / BN, 1);
                smk_ffn1<<<g1, 256, 0, stream>>>(x, W1, H, 1, e);
                dim3 g2(N_TOK / BM, C_DIM / BN, 1);
                smk_ffn2<<<g2, 256, 0, stream>>>(H, W2, scores, thr, eo, 1, e);
            }
        }
        smk_combine2<<<N_TOK, 256, 0, stream>>>(eo, scores, thr, fin);
    }
}

// Round 8
// 534.072 us; speedup vs baseline: 1.2029x; 1.2029x over previous
//
#include <hip/hip_runtime.h>
#include <hip/hip_bf16.h>
#include <math.h>
#include <stdint.h>

#define N_TOK 4096
#define C_DIM 1024
#define E_NUM 16
#define I_DIM 256

typedef unsigned short ushort_t;
typedef __attribute__((ext_vector_type(8))) short bf16x8;
typedef __attribute__((ext_vector_type(4))) float f32x4;

#define AS1 __attribute__((address_space(1)))
#define AS3 __attribute__((address_space(3)))

__device__ __forceinline__ void glds16(const void* g, void* l) {
    __builtin_amdgcn_global_load_lds((const AS1 uint32_t*)g, (AS3 uint32_t*)l, 16, 0, 0);
}

__device__ __forceinline__ ushort_t bf16_rne(float v) {
    uint32_t u = __float_as_uint(v);
    u = (u + 0x7FFFu + ((u >> 16) & 1u)) >> 16;
    return (ushort_t)u;
}
__device__ __forceinline__ float bf16_val(ushort_t h) {
    return __uint_as_float(((uint32_t)h) << 16);
}
__device__ __forceinline__ float gelu_exact(float v) {
    return 0.5f * v * (1.0f + erff(v * 0.70710678118654752f));
}

// ============================================================================
// smk_split: fp32 [R][K] -> hi+lo split-panel format.
// ============================================================================
__global__ __launch_bounds__(256) void smk_split(
    const float* __restrict__ src, char* __restrict__ dst, int R, int kush)
{
    const int u  = blockIdx.x * 256 + threadIdx.x;
    const int ku = 1 << kush;
    const int r  = u >> kush;
    const int k8 = u & (ku - 1);
    const int p  = k8 >> 2;
    const int uh = (k8 & 3) ^ (r & 7);

    const float* s = src + ((size_t)r << (kush + 3)) + k8 * 8;
    float4 a = *(const float4*)(s);
    float4 b = *(const float4*)(s + 4);
    float f[8] = {a.x, a.y, a.z, a.w, b.x, b.y, b.z, b.w};

    uint4 hi4, lo4;
    ushort_t* hp = (ushort_t*)&hi4;
    ushort_t* lp = (ushort_t*)&lo4;
    #pragma unroll
    for (int j = 0; j < 8; ++j) {
        ushort_t h = bf16_rne(f[j]);
        hp[j] = h;
        lp[j] = bf16_rne(f[j] - bf16_val(h));
    }
    size_t ob = (((size_t)p * R + r) * 8 + uh) * 16;
    *(uint4*)(dst + ob)        = hi4;
    *(uint4*)(dst + (ob ^ 64)) = lo4;
}

// ============================================================================
// smk_splitBH: fp32 [R][K] -> hi-only DUAL-PANEL format (W1 B-side).
// ============================================================================
__global__ __launch_bounds__(256) void smk_splitBH(
    const float* __restrict__ src, char* __restrict__ dst, int R, int kush)
{
    const int u  = blockIdx.x * 256 + threadIdx.x;
    const int ku = 1 << kush;
    const int r  = u >> kush;
    const int k8 = u & (ku - 1);
    const int p  = k8 >> 2;
    const int q  = p >> 1;
    const int uh = ((k8 & 3) | ((p & 1) << 2)) ^ (r & 7);

    const float* s = src + ((size_t)r << (kush + 3)) + k8 * 8;
    float4 a = *(const float4*)(s);
    float4 b = *(const float4*)(s + 4);
    float f[8] = {a.x, a.y, a.z, a.w, b.x, b.y, b.z, b.w};

    uint4 hi4;
    ushort_t* hp = (ushort_t*)&hi4;
    #pragma unroll
    for (int j = 0; j < 8; ++j) hp[j] = bf16_rne(f[j]);

    *(uint4*)(dst + (((size_t)q * R + r) * 8 + uh) * 16) = hi4;
}

// ============================================================================
// gate: 16 tokens per block; writes scores, kpt, and per-token activity mask.
// NO atomics.
// ============================================================================
__global__ __launch_bounds__(256) void smk_gate2(
    const float* __restrict__ x, const float* __restrict__ sim,
    const float* __restrict__ thr,
    float* __restrict__ scores, float* __restrict__ kpt,
    unsigned* __restrict__ maskArr)
{
    __shared__ __align__(16) float ss[C_DIM * E_NUM];
    __shared__ float pm[16][17];
    __shared__ float inv_ns[E_NUM];
    __shared__ float mrow[16][17];

    const int tid = threadIdx.x;
    #pragma unroll
    for (int q = 0; q < 16; ++q)
        *(float4*)&ss[q * 1024 + tid * 4] = *(const float4*)&sim[q * 1024 + tid * 4];
    __syncthreads();

    const int e = tid & 15;
    const int g = tid >> 4;
    float ps = 0.f;
    for (int c = g; c < C_DIM; c += 16) {
        float v = ss[c * 16 + e];
        ps = fmaf(v, v, ps);
    }
    pm[g][e] = ps;
    __syncthreads();
    if (tid < 16) {
        float s = 0.f;
        #pragma unroll
        for (int gg = 0; gg < 16; ++gg) s += pm[gg][tid];
        inv_ns[tid] = 1.f / fmaxf(sqrtf(s), 1e-12f);
    }
    __syncthreads();

    const int t = blockIdx.x * 16 + g;
    const float* xr = x + (size_t)t * C_DIM;
    float dot = 0.f, sq = 0.f;
    for (int c = 0; c < C_DIM; c += 4) {
        float4 xv = *(const float4*)&xr[c];
        dot = fmaf(xv.x, ss[(c + 0) * 16 + e], dot);
        dot = fmaf(xv.y, ss[(c + 1) * 16 + e], dot);
        dot = fmaf(xv.z, ss[(c + 2) * 16 + e], dot);
        dot = fmaf(xv.w, ss[(c + 3) * 16 + e], dot);
        sq  = fmaf(xv.x, xv.x, sq); sq = fmaf(xv.y, xv.y, sq);
        sq  = fmaf(xv.z, xv.z, sq); sq = fmaf(xv.w, xv.w, sq);
    }
    float sc = dot * inv_ns[e] * (1.f / fmaxf(sqrtf(sq), 1e-12f));
    scores[(size_t)t * E_NUM + e] = sc;
    mrow[g][e] = (sc > thr[0]) ? 1.f : 0.f;
    __syncthreads();
    if (e == 0) {
        float k = 0.f;
        unsigned mb = 0;
        #pragma unroll
        for (int ee = 0; ee < 16; ++ee) {
            if (mrow[g][ee] > 0.5f) { k += 1.f; mb |= (1u << ee); }
        }
        kpt[t] = k;
        if (maskArr) maskArr[t] = mb;
    }
}

// ============================================================================
// smk_lists: per-expert sorted compacted token list via block prefix-scan.
// Grid (E_NUM), 256 threads; thread handles 16 tokens. Deterministic,
// ascending token order (gather/scatter become near-streaming).
// ============================================================================
__global__ __launch_bounds__(256) void smk_lists(
    const unsigned* __restrict__ maskArr, int* __restrict__ lists,
    int* __restrict__ cnt)
{
    const int e   = blockIdx.x;
    const int tid = threadIdx.x;
    __shared__ int psum[256];

    unsigned mybits = 0;
    int cntl = 0;
    #pragma unroll
    for (int j = 0; j < 16; ++j) {
        if ((maskArr[tid * 16 + j] >> e) & 1u) { mybits |= (1u << j); ++cntl; }
    }
    psum[tid] = cntl;
    __syncthreads();
    // Hillis-Steele inclusive scan
    for (int s = 1; s < 256; s <<= 1) {
        int add = (tid >= s) ? psum[tid - s] : 0;
        __syncthreads();
        psum[tid] += add;
        __syncthreads();
    }
    int base = psum[tid] - cntl;   // exclusive prefix
    if (tid == 255) cnt[e] = psum[255];
    int* le = lists + e * N_TOK;
    #pragma unroll
    for (int j = 0; j < 16; ++j) {
        if ((mybits >> j) & 1u) le[base++] = tid * 16 + j;
    }
}

// ============================================================================
// COMPACTED FFN1: H[slot] = gelu(X[list[slot]] @ W1[e]^T).
// ============================================================================
__global__ __launch_bounds__(256) void smk_ffn1_mfma_c(
    const char* __restrict__ Xs, const char* __restrict__ W1h,
    char* __restrict__ Hsh, const int* __restrict__ lists,
    const int* __restrict__ cnt)
{
    __shared__ char As[16384];
    __shared__ char Bs[16384];

    const int e  = blockIdx.z;
    const int nt = cnt[e];
    const int t0 = blockIdx.x * 128;
    if (t0 >= nt) return;
    const int i0 = blockIdx.y * 128;
    const int tid  = threadIdx.x;
    const int lane = tid & 63;
    const int w    = tid >> 6;
    const int wr   = w >> 1, wc = w & 1;

    const int srow = tid >> 3;
    const int v    = tid & 7;
    const int* le  = lists + e * N_TOK;
    uint32_t abase[4];
    #pragma unroll
    for (int q = 0; q < 4; ++q) {
        int s    = q * 32 + srow;
        int slot = t0 + s;
        int tr   = le[(slot < nt) ? slot : (nt - 1)];
        abase[q] = (uint32_t)(tr * 128 + (v ^ ((s ^ tr) & 7)) * 16);
    }

    f32x4 acc[4][4];
    #pragma unroll
    for (int mi = 0; mi < 4; ++mi)
        #pragma unroll
        for (int ni = 0; ni < 4; ++ni)
            acc[mi][ni] = (f32x4){0.f, 0.f, 0.f, 0.f};

    const char* Bg = W1h + ((size_t)(e * 256) + i0) * 128 + tid * 16;

    for (int p = 0; p < 32; ++p) {
        __syncthreads();
        const char* gp = Xs + (size_t)p * (4096 * 128);
        #pragma unroll
        for (int q = 0; q < 4; ++q)
            glds16(gp + abase[q], As + q * 4096 + tid * 16);
        if ((p & 1) == 0) {
            const char* gb = Bg + (size_t)(p >> 1) * (4096 * 128);
            #pragma unroll
            for (int q = 0; q < 4; ++q)
                glds16(gb + q * 4096, Bs + q * 4096 + tid * 16);
        }
        __syncthreads();

        bf16x8 ah[4], al[4], bh[4];
        #pragma unroll
        for (int mi = 0; mi < 4; ++mi) {
            int r   = wr * 64 + mi * 16 + (lane & 15);
            int ubh = (((lane >> 4)    ) ^ (r & 7)) * 16;
            int ubl = (((lane >> 4) | 4) ^ (r & 7)) * 16;
            ah[mi] = *(const bf16x8*)(As + r * 128 + ubh);
            al[mi] = *(const bf16x8*)(As + r * 128 + ubl);
        }
        const int ubsel = (lane >> 4) | ((p & 1) << 2);
        #pragma unroll
        for (int ni = 0; ni < 4; ++ni) {
            int r  = wc * 64 + ni * 16 + (lane & 15);
            int ub = (ubsel ^ (r & 7)) * 16;
            bh[ni] = *(const bf16x8*)(Bs + r * 128 + ub);
        }
        #pragma unroll
        for (int mi = 0; mi < 4; ++mi)
            #pragma unroll
            for (int ni = 0; ni < 4; ++ni) {
                acc[mi][ni] = __builtin_amdgcn_mfma_f32_16x16x32_bf16(ah[mi], bh[ni], acc[mi][ni], 0, 0, 0);
                acc[mi][ni] = __builtin_amdgcn_mfma_f32_16x16x32_bf16(al[mi], bh[ni], acc[mi][ni], 0, 0, 0);
            }
    }

    const int rb = (lane >> 4) * 4;
    #pragma unroll
    for (int mi = 0; mi < 4; ++mi)
        #pragma unroll
        for (int ni = 0; ni < 4; ++ni) {
            int ig = i0 + wc * 64 + ni * 16 + (lane & 15);
            int pp = ig >> 5, qq = pp >> 1;
            int uu = ((ig >> 3) & 3) | ((pp & 1) << 2);
            #pragma unroll
            for (int j = 0; j < 4; ++j) {
                int slot = t0 + wr * 64 + mi * 16 + rb + j;
                float vv = gelu_exact(acc[mi][ni][j]);
                size_t ob = (((size_t)((e * 4 + qq) * 4096 + slot)) * 8 + (uu ^ (slot & 7))) * 16
                          + (ig & 7) * 2;
                *(ushort_t*)(Hsh + ob) = bf16_rne(vv);
            }
        }
}

// ============================================================================
// COMPACTED FFN2: eo[list[slot], e, :] = H[slot] @ W2[e]^T.
// ============================================================================
__global__ __launch_bounds__(256) void smk_ffn2_mfma_c(
    const char* __restrict__ Hsh, const char* __restrict__ W2s,
    const int* __restrict__ lists, const int* __restrict__ cnt,
    float* __restrict__ eo)
{
    __shared__ char As[16384];
    __shared__ char Bs[16384];

    const int e  = blockIdx.z;
    const int nt = cnt[e];
    const int t0 = blockIdx.x * 128;
    if (t0 >= nt) return;
    const int c0 = blockIdx.y * 128;
    const int tid  = threadIdx.x;
    const int lane = tid & 63;
    const int w    = tid >> 6;
    const int wr   = w >> 1, wc = w & 1;

    f32x4 acc[4][4];
    #pragma unroll
    for (int mi = 0; mi < 4; ++mi)
        #pragma unroll
        for (int ni = 0; ni < 4; ++ni)
            acc[mi][ni] = (f32x4){0.f, 0.f, 0.f, 0.f};

    const char* Ag = Hsh + ((size_t)(e * 4) * 4096 + t0) * 128 + tid * 16;
    const char* Bg = W2s + ((size_t)(e * 1024) + c0) * 128 + tid * 16;

    for (int p = 0; p < 8; ++p) {
        __syncthreads();
        if ((p & 1) == 0) {
            const char* ga = Ag + (size_t)(p >> 1) * (4096 * 128);
            #pragma unroll
            for (int q = 0; q < 4; ++q)
                glds16(ga + q * 4096, As + q * 4096 + tid * 16);
        }
        const char* gb = Bg + (size_t)p * (16384 * 128);
        #pragma unroll
        for (int q = 0; q < 4; ++q)
            glds16(gb + q * 4096, Bs + q * 4096 + tid * 16);
        __syncthreads();

        bf16x8 ah[4], bh[4], bl[4];
        const int uasel = (lane >> 4) | ((p & 1) << 2);
        #pragma unroll
        for (int mi = 0; mi < 4; ++mi) {
            int r  = wr * 64 + mi * 16 + (lane & 15);
            int ua = (uasel ^ (r & 7)) * 16;
            ah[mi] = *(const bf16x8*)(As + r * 128 + ua);
        }
        #pragma unroll
        for (int ni = 0; ni < 4; ++ni) {
            int r   = wc * 64 + ni * 16 + (lane & 15);
            int ubh = (((lane >> 4)    ) ^ (r & 7)) * 16;
            int ubl = (((lane >> 4) | 4) ^ (r & 7)) * 16;
            bh[ni] = *(const bf16x8*)(Bs + r * 128 + ubh);
            bl[ni] = *(const bf16x8*)(Bs + r * 128 + ubl);
        }
        #pragma unroll
        for (int mi = 0; mi < 4; ++mi)
            #pragma unroll
            for (int ni = 0; ni < 4; ++ni) {
                acc[mi][ni] = __builtin_amdgcn_mfma_f32_16x16x32_bf16(ah[mi], bh[ni], acc[mi][ni], 0, 0, 0);
                acc[mi][ni] = __builtin_amdgcn_mfma_f32_16x16x32_bf16(ah[mi], bl[ni], acc[mi][ni], 0, 0, 0);
            }
    }

    const int* le = lists + e * N_TOK;
    const int rb = (lane >> 4) * 4;
    #pragma unroll
    for (int mi = 0; mi < 4; ++mi)
        #pragma unroll
        for (int j = 0; j < 4; ++j) {
            int slot = t0 + wr * 64 + mi * 16 + rb + j;
            if (slot < nt) {
                int tr = le[slot];
                float* dst = eo + ((size_t)tr * E_NUM + e) * C_DIM + c0 + wc * 64 + (lane & 15);
                #pragma unroll
                for (int ni = 0; ni < 4; ++ni)
                    dst[ni * 16] = acc[mi][ni][j];
            }
        }
}

// ============================================================================
// zero-fill inactive eo rows
// ============================================================================
__global__ __launch_bounds__(256) void smk_zerofill(
    const float* __restrict__ scores, const float* __restrict__ thr,
    float* __restrict__ eo)
{
    const int row = blockIdx.x;
    if (scores[row] > thr[0]) return;
    float4 z = {0.f, 0.f, 0.f, 0.f};
    *(float4*)&eo[(size_t)row * C_DIM + threadIdx.x * 4] = z;
}

// ============================================================================
// combine: final[t] = sum over ACTIVE e of eo[t,e,:]
// ============================================================================
__global__ __launch_bounds__(256) void smk_combine2(
    const float* __restrict__ eo, const float* __restrict__ scores,
    const float* __restrict__ thr, float* __restrict__ fin)
{
    const int t = blockIdx.x;
    __shared__ unsigned am;
    if (threadIdx.x == 0) {
        unsigned m = 0;
        float th = thr[0];
        #pragma unroll
        for (int e = 0; e < E_NUM; ++e)
            if (scores[t * E_NUM + e] > th) m |= (1u << e);
        am = m;
    }
    __syncthreads();
    const unsigned m = am;
    const float* p = eo + (size_t)t * E_NUM * C_DIM + threadIdx.x * 4;
    float4 s = {0.f, 0.f, 0.f, 0.f};
    #pragma unroll
    for (int e = 0; e < E_NUM; ++e) {
        if (m & (1u << e)) {
            float4 v = *(const float4*)&p[(size_t)e * C_DIM];
            s.x += v.x; s.y += v.y; s.z += v.z; s.w += v.w;
        }
    }
    *(float4*)&fin[(size_t)t * C_DIM + threadIdx.x * 4] = s;
}

// ============================================================================
// DENSE MFMA path (round-6, proven) — fallback
// ============================================================================
__global__ __launch_bounds__(256) void smk_ffn1_mfma(
    const char* __restrict__ Xs, const char* __restrict__ W1h,
    char* __restrict__ Hsh)
{
    __shared__ char As[16384];
    __shared__ char Bs[16384];

    const int e  = blockIdx.z;
    const int t0 = blockIdx.x * 128;
    const int i0 = blockIdx.y * 128;
    const int tid  = threadIdx.x;
    const int lane = tid & 63;
    const int w    = tid >> 6;
    const int wr   = w >> 1, wc = w & 1;

    f32x4 acc[4][4];
    #pragma unroll
    for (int mi = 0; mi < 4; ++mi)
        #pragma unroll
        for (int ni = 0; ni < 4; ++ni)
            acc[mi][ni] = (f32x4){0.f, 0.f, 0.f, 0.f};

    const char* Ag = Xs  + (size_t)t0 * 128 + tid * 16;
    const char* Bg = W1h + ((size_t)(e * 256) + i0) * 128 + tid * 16;

    for (int p = 0; p < 32; ++p) {
        __syncthreads();
        const char* ga = Ag + (size_t)p * (4096 * 128);
        #pragma unroll
        for (int q = 0; q < 4; ++q)
            glds16(ga + q * 4096, As + q * 4096 + tid * 16);
        if ((p & 1) == 0) {
            const char* gb = Bg + (size_t)(p >> 1) * (4096 * 128);
            #pragma unroll
            for (int q = 0; q < 4; ++q)
                glds16(gb + q * 4096, Bs + q * 4096 + tid * 16);
        }
        __syncthreads();

        bf16x8 ah[4], al[4], bh[4];
        #pragma unroll
        for (int mi = 0; mi < 4; ++mi) {
            int r   = wr * 64 + mi * 16 + (lane & 15);
            int ubh = (((lane >> 4)    ) ^ (r & 7)) * 16;
            int ubl = (((lane >> 4) | 4) ^ (r & 7)) * 16;
            ah[mi] = *(const bf16x8*)(As + r * 128 + ubh);
            al[mi] = *(const bf16x8*)(As + r * 128 + ubl);
        }
        const int ubsel = (lane >> 4) | ((p & 1) << 2);
        #pragma unroll
        for (int ni = 0; ni < 4; ++ni) {
            int r  = wc * 64 + ni * 16 + (lane & 15);
            int ub = (ubsel ^ (r & 7)) * 16;
            bh[ni] = *(const bf16x8*)(Bs + r * 128 + ub);
        }
        #pragma unroll
        for (int mi = 0; mi < 4; ++mi)
            #pragma unroll
            for (int ni = 0; ni < 4; ++ni) {
                acc[mi][ni] = __builtin_amdgcn_mfma_f32_16x16x32_bf16(ah[mi], bh[ni], acc[mi][ni], 0, 0, 0);
                acc[mi][ni] = __builtin_amdgcn_mfma_f32_16x16x32_bf16(al[mi], bh[ni], acc[mi][ni], 0, 0, 0);
            }
    }

    const int rb = (lane >> 4) * 4;
    #pragma unroll
    for (int mi = 0; mi < 4; ++mi)
        #pragma unroll
        for (int ni = 0; ni < 4; ++ni) {
            int ig = i0 + wc * 64 + ni * 16 + (lane & 15);
            int pp = ig >> 5, qq = pp >> 1;
            int uu = ((ig >> 3) & 3) | ((pp & 1) << 2);
            #pragma unroll
            for (int j = 0; j < 4; ++j) {
                int t = t0 + wr * 64 + mi * 16 + rb + j;
                float vv = gelu_exact(acc[mi][ni][j]);
                size_t ob = (((size_t)((e * 4 + qq) * 4096 + t)) * 8 + (uu ^ (t & 7))) * 16
                          + (ig & 7) * 2;
                *(ushort_t*)(Hsh + ob) = bf16_rne(vv);
            }
        }
}

__global__ __launch_bounds__(256) void smk_ffn2_mfma(
    const char* __restrict__ Hsh, const char* __restrict__ W2s,
    const float* __restrict__ scores, const float* __restrict__ thr,
    float* __restrict__ eo)
{
    __shared__ char As[16384];
    __shared__ char Bs[16384];

    const int e  = blockIdx.z;
    const int t0 = blockIdx.x * 128;
    const int c0 = blockIdx.y * 128;
    const int tid  = threadIdx.x;
    const int lane = tid & 63;
    const int w    = tid >> 6;
    const int wr   = w >> 1, wc = w & 1;

    f32x4 acc[4][4];
    #pragma unroll
    for (int mi = 0; mi < 4; ++mi)
        #pragma unroll
        for (int ni = 0; ni < 4; ++ni)
            acc[mi][ni] = (f32x4){0.f, 0.f, 0.f, 0.f};

    const char* Ag = Hsh + ((size_t)(e * 4) * 4096 + t0) * 128 + tid * 16;
    const char* Bg = W2s + ((size_t)(e * 1024) + c0) * 128 + tid * 16;

    for (int p = 0; p < 8; ++p) {
        __syncthreads();
        if ((p & 1) == 0) {
            const char* ga = Ag + (size_t)(p >> 1) * (4096 * 128);
            #pragma unroll
            for (int q = 0; q < 4; ++q)
                glds16(ga + q * 4096, As + q * 4096 + tid * 16);
        }
        const char* gb = Bg + (size_t)p * (16384 * 128);
        #pragma unroll
        for (int q = 0; q < 4; ++q)
            glds16(gb + q * 4096, Bs + q * 4096 + tid * 16);
        __syncthreads();

        bf16x8 ah[4], bh[4], bl[4];
        const int uasel = (lane >> 4) | ((p & 1) << 2);
        #pragma unroll
        for (int mi = 0; mi < 4; ++mi) {
            int r  = wr * 64 + mi * 16 + (lane & 15);
            int ua = (uasel ^ (r & 7)) * 16;
            ah[mi] = *(const bf16x8*)(As + r * 128 + ua);
        }
        #pragma unroll
        for (int ni = 0; ni < 4; ++ni) {
            int r   = wc * 64 + ni * 16 + (lane & 15);
            int ubh = (((lane >> 4)    ) ^ (r & 7)) * 16;
            int ubl = (((lane >> 4) | 4) ^ (r & 7)) * 16;
            bh[ni] = *(const bf16x8*)(Bs + r * 128 + ubh);
            bl[ni] = *(const bf16x8*)(Bs + r * 128 + ubl);
        }
        #pragma unroll
        for (int mi = 0; mi < 4; ++mi)
            #pragma unroll
            for (int ni = 0; ni < 4; ++ni) {
                acc[mi][ni] = __builtin_amdgcn_mfma_f32_16x16x32_bf16(ah[mi], bh[ni], acc[mi][ni], 0, 0, 0);
                acc[mi][ni] = __builtin_amdgcn_mfma_f32_16x16x32_bf16(ah[mi], bl[ni], acc[mi][ni], 0, 0, 0);
            }
    }

    const float th = thr[0];
    const int rb = (lane >> 4) * 4;
    float msk[4][4];
    #pragma unroll
    for (int mi = 0; mi < 4; ++mi)
        #pragma unroll
        for (int j = 0; j < 4; ++j) {
            int t = t0 + wr * 64 + mi * 16 + rb + j;
            msk[mi][j] = (scores[(size_t)t * E_NUM + e] > th) ? 1.f : 0.f;
        }
    #pragma unroll
    for (int mi = 0; mi < 4; ++mi)
        #pragma unroll
        for (int ni = 0; ni < 4; ++ni) {
            int c = c0 + wc * 64 + ni * 16 + (lane & 15);
            #pragma unroll
            for (int j = 0; j < 4; ++j) {
                int t = t0 + wr * 64 + mi * 16 + rb + j;
                eo[((size_t)t * E_NUM + e) * C_DIM + c] = acc[mi][ni][j] * msk[mi][j];
            }
        }
}

// ============================================================================
// fp32 fallback path
// ============================================================================
#define BM 64
#define BN 64
#define KC 16
#define LDP 68

__global__ __launch_bounds__(256) void smk_ffn1(
    const float* __restrict__ X, const float* __restrict__ W1,
    float* __restrict__ H, int eh, int ez0)
{
    const int e  = blockIdx.z + ez0;
    const int t0 = blockIdx.x * BM;
    const int i0 = blockIdx.y * BN;
    const float* Ap = X + (size_t)t0 * C_DIM;
    const float* Bp = W1 + ((size_t)e * I_DIM + i0) * C_DIM;
    __shared__ __align__(16) float As[KC][LDP];
    __shared__ __align__(16) float Bs[KC][LDP];
    const int tid = threadIdx.x;
    const int tx = tid & 15, ty = tid >> 4;
    const int lm = tid >> 2;
    const int lk = (tid & 3) * 4;
    float acc[4][4] = {};
    for (int k0 = 0; k0 < C_DIM; k0 += KC) {
        float4 av = *(const float4*)&Ap[(size_t)lm * C_DIM + k0 + lk];
        float4 bv = *(const float4*)&Bp[(size_t)lm * C_DIM + k0 + lk];
        __syncthreads();
        As[lk + 0][lm] = av.x; As[lk + 1][lm] = av.y;
        As[lk + 2][lm] = av.z; As[lk + 3][lm] = av.w;
        Bs[lk + 0][lm] = bv.x; Bs[lk + 1][lm] = bv.y;
        Bs[lk + 2][lm] = bv.z; Bs[lk + 3][lm] = bv.w;
        __syncthreads();
        #pragma unroll
        for (int k = 0; k < KC; ++k) {
            float4 a4 = *(const float4*)&As[k][ty * 4];
            float4 b4 = *(const float4*)&Bs[k][tx * 4];
            float a[4] = {a4.x, a4.y, a4.z, a4.w};
            float b[4] = {b4.x, b4.y, b4.z, b4.w};
            #pragma unroll
            for (int i = 0; i < 4; ++i)
                #pragma unroll
                for (int j = 0; j < 4; ++j)
                    acc[i][j] = fmaf(a[i], b[j], acc[i][j]);
        }
    }
    const size_t hrow = (size_t)eh * I_DIM;
    float* Hp = H + ((eh == E_NUM) ? (size_t)e * I_DIM : 0);
    #pragma unroll
    for (int i = 0; i < 4; ++i) {
        int t = t0 + ty * 4 + i;
        float4 o;
        o.x = gelu_exact(acc[i][0]); o.y = gelu_exact(acc[i][1]);
        o.z = gelu_exact(acc[i][2]); o.w = gelu_exact(acc[i][3]);
        *(float4*)&Hp[(size_t)t * hrow + i0 + tx * 4] = o;
    }
}

__global__ __launch_bounds__(256) void smk_ffn2(
    const float* __restrict__ Hst, const float* __restrict__ W2,
    const float* __restrict__ scores, const float* __restrict__ thr,
    float* __restrict__ eo, int eh, int ez0)
{
    const int e  = blockIdx.z + ez0;
    const int t0 = blockIdx.x * BM;
    const int c0 = blockIdx.y * BN;
    const size_t hrow = (size_t)eh * I_DIM;
    const float* Ap = Hst + ((eh == E_NUM) ? (size_t)e * I_DIM : 0) + (size_t)t0 * hrow;
    const float* Bp = W2 + ((size_t)e * C_DIM + c0) * I_DIM;
    __shared__ __align__(16) float As[KC][LDP];
    __shared__ __align__(16) float Bs[KC][LDP];
    const int tid = threadIdx.x;
    const int tx = tid & 15, ty = tid >> 4;
    const int lm = tid >> 2;
    const int lk = (tid & 3) * 4;
    float acc[4][4] = {};
    for (int k0 = 0; k0 < I_DIM; k0 += KC) {
        float4 av = *(const float4*)&Ap[(size_t)lm * hrow + k0 + lk];
        float4 bv = *(const float4*)&Bp[(size_t)lm * I_DIM + k0 + lk];
        __syncthreads();
        As[lk + 0][lm] = av.x; As[lk + 1][lm] = av.y;
        As[lk + 2][lm] = av.z; As[lk + 3][lm] = av.w;
        Bs[lk + 0][lm] = bv.x; Bs[lk + 1][lm] = bv.y;
        Bs[lk + 2][lm] = bv.z; Bs[lk + 3][lm] = bv.w;
        __syncthreads();
        #pragma unroll
        for (int k = 0; k < KC; ++k) {
            float4 a4 = *(const float4*)&As[k][ty * 4];
            float4 b4 = *(const float4*)&Bs[k][tx * 4];
            float a[4] = {a4.x, a4.y, a4.z, a4.w};
            float b[4] = {b4.x, b4.y, b4.z, b4.w};
            #pragma unroll
            for (int i = 0; i < 4; ++i)
                #pragma unroll
                for (int j = 0; j < 4; ++j)
                    acc[i][j] = fmaf(a[i], b[j], acc[i][j]);
        }
    }
    const float th = thr[0];
    #pragma unroll
    for (int i = 0; i < 4; ++i) {
        int t = t0 + ty * 4 + i;
        float m = (scores[(size_t)t * E_NUM + e] > th) ? 1.f : 0.f;
        float4 o;
        o.x = acc[i][0] * m; o.y = acc[i][1] * m;
        o.z = acc[i][2] * m; o.w = acc[i][3] * m;
        *(float4*)&eo[((size_t)t * E_NUM + e) * C_DIM + c0 + tx * 4] = o;
    }
}

// ============================================================================
extern "C" void kernel_launch(void* const* d_in, const int* in_sizes, int n_in,
                              void* d_out, int out_size, void* d_ws, size_t ws_size,
                              hipStream_t stream) {
    const float* x   = (const float*)d_in[0];
    const float* sim = (const float*)d_in[1];
    const float* thr = (const float*)d_in[2];
    const float* W1  = (const float*)d_in[3];
    const float* W2  = (const float*)d_in[4];

    float* out    = (float*)d_out;
    float* fin    = out;
    float* scores = out + (size_t)N_TOK * C_DIM;
    float* eo     = scores + (size_t)N_TOK * E_NUM;
    float* kpt    = eo + (size_t)N_TOK * E_NUM * C_DIM;

    const size_t SZ_XS  = 16777216;  // X hi+lo:  32p x 4096 x 128B
    const size_t SZ_W1H = 8388608;   // W1 hi:    16q x 4096 x 128B
    const size_t SZ_W2S = 16777216;  // W2 hi+lo:  8p x 16384 x 128B
    const size_t SZ_HSH = 33554432;  // H hi: 16e x 4q x 4096slots x 128B
    const size_t SZ_LST = (size_t)E_NUM * N_TOK * sizeof(int);  // 262144
    const size_t SZ_CNT = 64;
    const size_t SZ_MSK = (size_t)N_TOK * sizeof(unsigned);     // 16384
    const size_t WS_MFMA = SZ_XS + SZ_W1H + SZ_W2S + SZ_HSH;    // 75,497,472
    const size_t WS_FULL = WS_MFMA + SZ_LST + SZ_CNT + SZ_MSK;  // 75,776,064

    char* Xs  = (char*)d_ws;
    char* W1h = Xs + SZ_XS;
    char* W2s = W1h + SZ_W1H;
    char* Hsh = W2s + SZ_W2S;
    int*  lists = (int*)(Hsh + SZ_HSH);
    int*  cnt   = lists + E_NUM * N_TOK;
    unsigned* maskArr = (unsigned*)(cnt + 16);

    if (ws_size >= WS_FULL) {
        // ---- compacted MFMA path (sorted lists, no atomics) ----
        smk_gate2<<<N_TOK / 16, 256, 0, stream>>>(x, sim, thr, scores, kpt, maskArr);
        smk_lists<<<E_NUM, 256, 0, stream>>>(maskArr, lists, cnt);

        smk_split  <<<2048, 256, 0, stream>>>(x,  Xs,  4096,  7);
        smk_splitBH<<<2048, 256, 0, stream>>>(W1, W1h, 4096,  7);
        smk_split  <<<2048, 256, 0, stream>>>(W2, W2s, 16384, 5);

        dim3 g1(32, 2, 16);
        smk_ffn1_mfma_c<<<g1, 256, 0, stream>>>(Xs, W1h, Hsh, lists, cnt);
        dim3 g2(32, 8, 16);
        smk_ffn2_mfma_c<<<g2, 256, 0, stream>>>(Hsh, W2s, lists, cnt, eo);

        smk_zerofill<<<N_TOK * E_NUM, 256, 0, stream>>>(scores, thr, eo);
        smk_combine2<<<N_TOK, 256, 0, stream>>>(eo, scores, thr, fin);
    } else if (ws_size >= WS_MFMA) {
        // ---- dense MFMA path (round 6) ----
        smk_gate2<<<N_TOK / 16, 256, 0, stream>>>(x, sim, thr, scores, kpt, nullptr);
        smk_split  <<<2048, 256, 0, stream>>>(x,  Xs,  4096,  7);
        smk_splitBH<<<2048, 256, 0, stream>>>(W1, W1h, 4096,  7);
        smk_split  <<<2048, 256, 0, stream>>>(W2, W2s, 16384, 5);
        dim3 g1(32, 2, 16);
        smk_ffn1_mfma<<<g1, 256, 0, stream>>>(Xs, W1h, Hsh);
        dim3 g2(32, 8, 16);
        smk_ffn2_mfma<<<g2, 256, 0, stream>>>(Hsh, W2s, scores, thr, eo);
        smk_combine2<<<N_TOK, 256, 0, stream>>>(eo, scores, thr, fin);
    } else {
        // ---- fp32 fallback ----
        smk_gate2<<<N_TOK / 16, 256, 0, stream>>>(x, sim, thr, scores, kpt, nullptr);
        const size_t needH = (size_t)N_TOK * E_NUM * I_DIM * sizeof(float);
        if (ws_size >= needH) {
            float* H = (float*)d_ws;
            dim3 g1(N_TOK / BM, I_DIM / BN, E_NUM);
            smk_ffn1<<<g1, 256, 0, stream>>>(x, W1, H, E_NUM, 0);
            dim3 g2(N_TOK / BM, C_DIM / BN, E_NUM);
            smk_ffn2<<<g2, 256, 0, stream>>>(H, W2, scores, thr, eo, E_NUM, 0);
        } else {
            float* H = fin;
            for (int e = 0; e < E_NUM; ++e) {
                dim3 g1(N_TOK / BM, I_DIM / BN, 1);
                smk_ffn1<<<g1, 256, 0, stream>>>(x, W1, H, 1, e);
                dim3 g2(N_TOK / BM, C_DIM / BN, 1);
                smk_ffn2<<<g2, 256, 0, stream>>>(H, W2, scores, thr, eo, 1, e);
            }
        }
        smk_combine2<<<N_TOK, 256, 0, stream>>>(eo, scores, thr, fin);
    }
}